// Round 1
// baseline (143.428 us; speedup 1.0000x reference)
//
#include <hip/hip_runtime.h>

// SASA: B=2, CIN=192, H=W=56 (HW=3136), ODIM=192, HEADS=6 (d=32), K=7, PAD=3, STRIDE=1
// Pipeline: [gemm qkv] -> [windowed attention] -> [gemm proj]
// ws layout (floats): q[2][192][3136] | k[...] | v[...]  (3 * 1204224 floats = 14.45 MB)
// attention output o aliases the q region (each q element is read then written by the
// same thread, so no hazard).

#define HW    3136
#define WIMG  56
#define CIN   192
#define NCH   1204224   // 2*192*3136, size of one of q/k/v in floats

// ---------------------------------------------------------------------------
// Generic fp32 GEMM: Y[wsel*wstride + (b*192 + mrow0 + m)*HW + p] =
//   sum_c W[m,c] * X[(b*192+c)*HW + p]
// Tile 64(M) x 64(N), K-chunk 16, 256 threads, 4x4 microtile.
// grid = (49, mtiles, 2). W selected per 3 m-tiles (qkv: 9 tiles -> wq/wk/wv;
// proj: 3 tiles -> w_proj only).
// ---------------------------------------------------------------------------
__global__ __launch_bounds__(256) void gemm_kernel(
    const float* __restrict__ W0, const float* __restrict__ W1,
    const float* __restrict__ W2, const float* __restrict__ X,
    float* __restrict__ Y, int wstride)
{
    __shared__ float As[64][17];   // [m][kc] +1 pad
    __shared__ float Bs[16][68];   // [kc][p] +4 pad (keeps float4 alignment)

    const int tid = threadIdx.x;
    const int bx = blockIdx.x;          // n tile (0..48)
    const int my = blockIdx.y;          // m tile
    const int b  = blockIdx.z;

    const int wsel  = my / 3;
    const float* Wp = (wsel == 0) ? W0 : ((wsel == 1) ? W1 : W2);
    const int mrow0 = (my % 3) * 64;
    const int p0    = bx * 64;

    const int tm4 = (tid >> 4) * 4;     // m sub-offset 0..60
    const int tn4 = (tid & 15) * 4;     // n sub-offset 0..60

    // staging assignments
    const int arow = tid >> 2;          // 0..63 (m row)
    const int acq  = (tid & 3) * 4;     // c quad within chunk
    const int bkc  = tid >> 4;          // 0..15 (c row)
    const int bpq  = (tid & 15) * 4;    // p quad

    const float* Xb = X + (b * CIN) * HW + p0;

    float acc[4][4] = {};

    for (int c0 = 0; c0 < CIN; c0 += 16) {
        float4 av = *(const float4*)(Wp + (mrow0 + arow) * CIN + c0 + acq);
        float4 bv = *(const float4*)(Xb + (c0 + bkc) * HW + bpq);
        As[arow][acq + 0] = av.x;
        As[arow][acq + 1] = av.y;
        As[arow][acq + 2] = av.z;
        As[arow][acq + 3] = av.w;
        *(float4*)&Bs[bkc][bpq] = bv;
        __syncthreads();

        #pragma unroll
        for (int kc = 0; kc < 16; ++kc) {
            float a[4];
            #pragma unroll
            for (int i = 0; i < 4; ++i) a[i] = As[tm4 + i][kc];
            float4 bb = *(const float4*)&Bs[kc][tn4];
            float bf[4] = {bb.x, bb.y, bb.z, bb.w};
            #pragma unroll
            for (int i = 0; i < 4; ++i)
                #pragma unroll
                for (int j = 0; j < 4; ++j)
                    acc[i][j] = fmaf(a[i], bf[j], acc[i][j]);
        }
        __syncthreads();
    }

    float* Yb = Y + wsel * wstride + (b * CIN + mrow0 + tm4) * HW + p0 + tn4;
    #pragma unroll
    for (int i = 0; i < 4; ++i) {
        *(float4*)(Yb + i * HW) = make_float4(acc[i][0], acc[i][1], acc[i][2], acc[i][3]);
    }
}

// ---------------------------------------------------------------------------
// Windowed attention. grid = (7, 7, 12) [tileX, tileY, b*6+h], 256 threads.
// Block stages the 14x14 K/V patch (32 ch) for one head into LDS, then
// 4 threads cooperate per pixel (d split 4 x 8).
// ---------------------------------------------------------------------------
__global__ __launch_bounds__(256) void attn_kernel(
    const float* __restrict__ qkv,      // ws base (q at 0, k at NCH, v at 2*NCH)
    const float* __restrict__ pos,      // 13 floats
    float* __restrict__ o)              // aliases q region
{
    __shared__ float kbuf[196 * 34];    // [patch pixel][d], stride 34 (8B-aligned float2)
    __shared__ float vbuf[196 * 34];

    const int tid = threadIdx.x;
    const int tx = blockIdx.x, ty = blockIdx.y;
    const int bh = blockIdx.z;
    const int b = bh / 6, h = bh % 6;
    const int y0 = ty * 8 - 3, x0 = tx * 8 - 3;

    const float* kbase = qkv + NCH     + (b * CIN + h * 32) * HW;
    const float* vbase = qkv + 2 * NCH + (b * CIN + h * 32) * HW;

    // stage K/V patch (zero-fill outside the image == reference zero padding)
    for (int ii = tid; ii < 196 * 32; ii += 256) {
        int d  = ii / 196;
        int pp = ii - d * 196;
        int py = pp / 14;
        int px = pp - py * 14;
        int gy = y0 + py, gx = x0 + px;
        float kv = 0.f, vv = 0.f;
        if ((unsigned)gy < 56u && (unsigned)gx < 56u) {
            int off = d * HW + gy * WIMG + gx;
            kv = kbase[off];
            vv = vbase[off];
        }
        kbuf[pp * 34 + d] = kv;
        vbuf[pp * 34 + d] = vv;
    }
    __syncthreads();

    const int sub = tid & 3;            // d-quad: handles d = sub*8 .. sub*8+7
    const int pix = tid >> 2;           // 0..63 within 8x8 tile
    const int py = pix >> 3, px = pix & 7;
    const int y = ty * 8 + py, x = tx * 8 + px;

    const float* qbase = qkv + (b * CIN + h * 32 + sub * 8) * HW + y * WIMG + x;
    float q[8];
    #pragma unroll
    for (int j = 0; j < 8; ++j) q[j] = qbase[j * HW];

    float posr[13];
    #pragma unroll
    for (int i = 0; i < 13; ++i) posr[i] = pos[i];

    // QK^T (+ relative position bias)
    float logits[49];
    #pragma unroll
    for (int kk = 0; kk < 49; ++kk) {
        const int ky = kk / 7, kx = kk % 7;   // compile-time after unroll
        const int pp = (py + ky) * 14 + (px + kx);
        const float* kp = &kbuf[pp * 34 + sub * 8];
        float s = 0.f;
        #pragma unroll
        for (int j = 0; j < 8; ++j) s = fmaf(q[j], kp[j], s);
        s += __shfl_xor(s, 1);   // reduce across the 4 d-quads (adjacent lanes)
        s += __shfl_xor(s, 2);
        logits[kk] = s + posr[ky + kx];
    }

    // softmax over the 49 window positions
    float m = logits[0];
    #pragma unroll
    for (int kk = 1; kk < 49; ++kk) m = fmaxf(m, logits[kk]);
    float sum = 0.f;
    #pragma unroll
    for (int kk = 0; kk < 49; ++kk) {
        logits[kk] = __expf(logits[kk] - m);
        sum += logits[kk];
    }
    const float inv = 1.f / sum;

    // PV
    float acc[8] = {};
    #pragma unroll
    for (int kk = 0; kk < 49; ++kk) {
        const int ky = kk / 7, kx = kk % 7;
        const int pp = (py + ky) * 14 + (px + kx);
        const float* vp = &vbuf[pp * 34 + sub * 8];
        const float p = logits[kk] * inv;
        #pragma unroll
        for (int j = 0; j < 8; ++j) acc[j] = fmaf(p, vp[j], acc[j]);
    }

    float* obase = o + (b * CIN + h * 32 + sub * 8) * HW + y * WIMG + x;
    #pragma unroll
    for (int j = 0; j < 8; ++j) obase[j * HW] = acc[j];
}

// ---------------------------------------------------------------------------
extern "C" void kernel_launch(void* const* d_in, const int* in_sizes, int n_in,
                              void* d_out, int out_size, void* d_ws, size_t ws_size,
                              hipStream_t stream)
{
    const float* x     = (const float*)d_in[0];
    const float* wq    = (const float*)d_in[1];
    const float* wk    = (const float*)d_in[2];
    const float* wv    = (const float*)d_in[3];
    const float* pos   = (const float*)d_in[4];
    const float* wproj = (const float*)d_in[5];
    // d_in[6..9]: kernel_size/padding/stride/num_heads scalars — compile-time here.

    float* ws  = (float*)d_ws;
    float* out = (float*)d_out;

    // qkv: [576 x 192] x [192 x 3136] per batch -> ws
    gemm_kernel<<<dim3(49, 9, 2), 256, 0, stream>>>(wq, wk, wv, x, ws, NCH);
    // attention: reads q/k/v from ws, writes o over the q region
    attn_kernel<<<dim3(7, 7, 12), 256, 0, stream>>>(ws, pos, ws);
    // proj: [192 x 192] x [192 x 3136] per batch -> d_out
    gemm_kernel<<<dim3(49, 3, 2), 256, 0, stream>>>(wproj, wproj, wproj, ws, out, 0);
}

// Round 2
// 113.409 us; speedup vs baseline: 1.2647x; 1.2647x over previous
//
#include <hip/hip_runtime.h>

// SASA: B=2, CIN=192, H=W=56 (HW=3136), ODIM=192, HEADS=6 (d=32), K=7, PAD=3
// Pipeline: [prep: x->XT bf16 transpose + weights->bf16] -> [qkv bf16-MFMA GEMM]
//           -> [windowed attention fp32, writes o_act bf16] -> [proj bf16-MFMA GEMM]
//
// ws layout (bytes):
//   XT   [2][3136][192] bf16 @ 0        (2,408,448 B)  x transposed, c contiguous
//   WB   [768][192]     bf16 @ 2408448  (294,912 B)    wq|wk|wv|wproj rows
//   QKV  [2][3136][576] f32  @ 2703360  (14,450,688 B) q ch 0-191 | k 192-383 | v 384-575
//   OACT [2][3136][192] bf16 @ 17154048 (2,408,448 B)  attention out, proj's B operand

#define HW    3136
#define WIMG  56
#define CIN   192
#define QKVLD 576

using short8 = __attribute__((ext_vector_type(8))) short;
using f32x4  = __attribute__((ext_vector_type(4))) float;

__device__ __forceinline__ unsigned short f2bf(float f) {
    union { float f; unsigned int u; } v; v.f = f;
    unsigned int r = v.u + 0x7fffu + ((v.u >> 16) & 1u);
    return (unsigned short)(r >> 16);
}

// ---------------------------------------------------------------------------
// prep: z<2 -> transpose x[b][c][p] fp32 -> XT[b][p][c] bf16 (64x64 tiles)
//       z==2 -> convert wq|wk|wv|wproj fp32 -> WB bf16 (natural [o][c] layout)
// ---------------------------------------------------------------------------
__global__ __launch_bounds__(256) void prep_kernel(
    const float* __restrict__ x,  const float* __restrict__ wq,
    const float* __restrict__ wk, const float* __restrict__ wv,
    const float* __restrict__ wproj,
    unsigned short* __restrict__ xt, unsigned short* __restrict__ wb)
{
    const int tid = threadIdx.x;
    if (blockIdx.z == 2) {
        int gid  = blockIdx.y * 49 + blockIdx.x;          // 0..146
        int base = (gid * 256 + tid) * 4;                 // float index
        if (base < 147456) {
            const float* src;
            if      (base <  36864) src = wq    + base;
            else if (base <  73728) src = wk    + base -  36864;
            else if (base < 110592) src = wv    + base -  73728;
            else                    src = wproj + base - 110592;
            float4 v = *(const float4*)src;
            ushort4 h;
            h.x = f2bf(v.x); h.y = f2bf(v.y); h.z = f2bf(v.z); h.w = f2bf(v.w);
            *(ushort4*)(wb + base) = h;
        }
        return;
    }
    __shared__ float t[64][68];
    const int b  = blockIdx.z;
    const int p0 = blockIdx.x * 64, c0 = blockIdx.y * 64;
    {
        const int r0 = tid >> 4, pq = (tid & 15) * 4;
        #pragma unroll
        for (int i = 0; i < 4; ++i) {
            int cc = r0 + 16 * i;
            float4 v = *(const float4*)(x + (size_t)(b * CIN + c0 + cc) * HW + p0 + pq);
            *(float4*)&t[cc][pq] = v;
        }
    }
    __syncthreads();
    #pragma unroll
    for (int i = 0; i < 2; ++i) {
        int u = tid + 256 * i;
        int pr = u >> 3, oct = u & 7;
        ushort4 h0, h1;
        h0.x = f2bf(t[oct*8+0][pr]); h0.y = f2bf(t[oct*8+1][pr]);
        h0.z = f2bf(t[oct*8+2][pr]); h0.w = f2bf(t[oct*8+3][pr]);
        h1.x = f2bf(t[oct*8+4][pr]); h1.y = f2bf(t[oct*8+5][pr]);
        h1.z = f2bf(t[oct*8+6][pr]); h1.w = f2bf(t[oct*8+7][pr]);
        unsigned short* dst = xt + ((size_t)(b * HW + p0 + pr) * CIN + c0 + oct * 8);
        *(ushort4*)dst       = h0;
        *(ushort4*)(dst + 4) = h1;
    }
}

// ---------------------------------------------------------------------------
// 64x64 bf16 MFMA GEMM, K=192 fully resident in LDS (single stage, 1 barrier).
// A: [M][192] bf16 row-major (m-operand), B: [N][192] bf16 row-major (n-operand)
// D[m][n] fp32 -> Y[row*ldY + col]. 4 waves, each a 32x32 quadrant (2x2 mfma).
// Rows padded to 400B: frag b128 reads conflict-free per quarter-wave.
// ---------------------------------------------------------------------------
__global__ __launch_bounds__(256) void gemm64(
    const unsigned short* __restrict__ A, long Ab,
    const unsigned short* __restrict__ B, long Bb,
    float* __restrict__ Y, long Yb, int ldY)
{
    __shared__ unsigned short As[64 * 200];   // 200 ushorts = 400B rows
    __shared__ unsigned short Bs[64 * 200];
    const int tid = threadIdx.x;

    A += blockIdx.z * Ab + (size_t)blockIdx.x * 64 * CIN;
    B += blockIdx.z * Bb + (size_t)blockIdx.y * 64 * CIN;
    Y += blockIdx.z * Yb + (size_t)blockIdx.x * 64 * ldY + blockIdx.y * 64;

    // stage both tiles: thread (r=tid>>2, c4=tid&3) covers octs c4+4i (64B/4 lanes)
    const int r = tid >> 2, c4 = tid & 3;
    #pragma unroll
    for (int i = 0; i < 6; ++i) {
        int oct = c4 + 4 * i;
        *(uint4*)(As + r * 200 + oct * 8) = *(const uint4*)(A + r * CIN + oct * 8);
        *(uint4*)(Bs + r * 200 + oct * 8) = *(const uint4*)(B + r * CIN + oct * 8);
    }
    __syncthreads();

    const int lane = tid & 63, wave = tid >> 6;
    const int wm = (wave & 1) * 32, wn = (wave >> 1) * 32;
    const int l15 = lane & 15, quad = lane >> 4;

    f32x4 acc[2][2] = {};
    const unsigned short* pa0 = As + (wm + l15) * 200 + quad * 8;
    const unsigned short* pb0 = Bs + (wn + l15) * 200 + quad * 8;

    #pragma unroll
    for (int s = 0; s < 6; ++s) {
        short8 a0 = *(const short8*)(pa0 + s * 32);
        short8 a1 = *(const short8*)(pa0 + 16 * 200 + s * 32);
        short8 b0 = *(const short8*)(pb0 + s * 32);
        short8 b1 = *(const short8*)(pb0 + 16 * 200 + s * 32);
        acc[0][0] = __builtin_amdgcn_mfma_f32_16x16x32_bf16(a0, b0, acc[0][0], 0, 0, 0);
        acc[0][1] = __builtin_amdgcn_mfma_f32_16x16x32_bf16(a0, b1, acc[0][1], 0, 0, 0);
        acc[1][0] = __builtin_amdgcn_mfma_f32_16x16x32_bf16(a1, b0, acc[1][0], 0, 0, 0);
        acc[1][1] = __builtin_amdgcn_mfma_f32_16x16x32_bf16(a1, b1, acc[1][1], 0, 0, 0);
    }

    // C/D layout: col=lane&15, row=quad*4+reg
    #pragma unroll
    for (int ti = 0; ti < 2; ++ti)
        #pragma unroll
        for (int tj = 0; tj < 2; ++tj)
            #pragma unroll
            for (int rr = 0; rr < 4; ++rr) {
                int row = wm + ti * 16 + quad * 4 + rr;
                int col = wn + tj * 16 + l15;
                Y[(size_t)row * ldY + col] = acc[ti][tj][rr];
            }
}

// ---------------------------------------------------------------------------
// Windowed attention. grid = (7,7,12), 256 threads. QKV layout [b][p][576].
// Stages 14x14 K/V patch (32 ch fp32) in LDS; 4 threads/pixel (d split 4x8).
// Writes o_act bf16 [b][p][192] (proj's natural B-operand layout).
// ---------------------------------------------------------------------------
__global__ __launch_bounds__(256) void attn_kernel(
    const float* __restrict__ qkv, const float* __restrict__ pos,
    unsigned short* __restrict__ oact)
{
    __shared__ float kbuf[196 * 34];   // [patch pixel][32 ch], stride 34 (8B-aligned rows)
    __shared__ float vbuf[196 * 34];

    const int tid = threadIdx.x;
    const int tx = blockIdx.x, ty = blockIdx.y;
    const int b = blockIdx.z / 6, h = blockIdx.z % 6;
    const int y0 = ty * 8 - 3, x0 = tx * 8 - 3;
    const int chk = 192 + h * 32, chv = 384 + h * 32;

    // stage: 3136 float4 units = 196 px * (8 k-units + 8 v-units)
    for (int ii = tid; ii < 3136; ii += 256) {
        int pp = ii >> 4, u = ii & 15;
        int py = pp / 14, px = pp - py * 14;
        int gy = y0 + py, gx = x0 + px;
        int isv = u >> 3, uu = u & 7;
        float4 val = make_float4(0.f, 0.f, 0.f, 0.f);
        if ((unsigned)gy < 56u && (unsigned)gx < 56u) {
            int p = gy * WIMG + gx;
            val = *(const float4*)(qkv + (size_t)(b * HW + p) * QKVLD + (isv ? chv : chk) + uu * 4);
        }
        float* dst = (isv ? vbuf : kbuf) + pp * 34 + uu * 4;
        *(float2*)dst       = make_float2(val.x, val.y);
        *(float2*)(dst + 2) = make_float2(val.z, val.w);
    }
    __syncthreads();

    const int sub = tid & 3, pix = tid >> 2;
    const int py = pix >> 3, px = pix & 7;
    const int y = ty * 8 + py, x = tx * 8 + px;
    const int p = y * WIMG + x;

    const float* qb = qkv + (size_t)(b * HW + p) * QKVLD + h * 32 + sub * 8;
    float4 q0 = *(const float4*)qb, q1 = *(const float4*)(qb + 4);

    float posr[13];
    #pragma unroll
    for (int i = 0; i < 13; ++i) posr[i] = pos[i];

    float logits[49];
    #pragma unroll
    for (int kk = 0; kk < 49; ++kk) {
        const int ky = kk / 7, kx = kk % 7;
        const int pp = (py + ky) * 14 + (px + kx);
        const float2* kp = (const float2*)(kbuf + pp * 34 + sub * 8);
        float2 k0 = kp[0], k1 = kp[1], k2 = kp[2], k3 = kp[3];
        float s = 0.f;
        s = fmaf(q0.x, k0.x, s); s = fmaf(q0.y, k0.y, s);
        s = fmaf(q0.z, k1.x, s); s = fmaf(q0.w, k1.y, s);
        s = fmaf(q1.x, k2.x, s); s = fmaf(q1.y, k2.y, s);
        s = fmaf(q1.z, k3.x, s); s = fmaf(q1.w, k3.y, s);
        s += __shfl_xor(s, 1);
        s += __shfl_xor(s, 2);
        logits[kk] = s + posr[ky + kx];
    }

    float m = logits[0];
    #pragma unroll
    for (int kk = 1; kk < 49; ++kk) m = fmaxf(m, logits[kk]);
    float sum = 0.f;
    #pragma unroll
    for (int kk = 0; kk < 49; ++kk) {
        logits[kk] = __expf(logits[kk] - m);
        sum += logits[kk];
    }
    const float inv = 1.f / sum;

    float acc[8] = {};
    #pragma unroll
    for (int kk = 0; kk < 49; ++kk) {
        const int ky = kk / 7, kx = kk % 7;
        const int pp = (py + ky) * 14 + (px + kx);
        const float2* vp = (const float2*)(vbuf + pp * 34 + sub * 8);
        float2 v0 = vp[0], v1 = vp[1], v2 = vp[2], v3 = vp[3];
        const float pw = logits[kk] * inv;
        acc[0] = fmaf(pw, v0.x, acc[0]); acc[1] = fmaf(pw, v0.y, acc[1]);
        acc[2] = fmaf(pw, v1.x, acc[2]); acc[3] = fmaf(pw, v1.y, acc[3]);
        acc[4] = fmaf(pw, v2.x, acc[4]); acc[5] = fmaf(pw, v2.y, acc[5]);
        acc[6] = fmaf(pw, v3.x, acc[6]); acc[7] = fmaf(pw, v3.y, acc[7]);
    }

    ushort4 h0, h1;
    h0.x = f2bf(acc[0]); h0.y = f2bf(acc[1]); h0.z = f2bf(acc[2]); h0.w = f2bf(acc[3]);
    h1.x = f2bf(acc[4]); h1.y = f2bf(acc[5]); h1.z = f2bf(acc[6]); h1.w = f2bf(acc[7]);
    unsigned short* ob = oact + ((size_t)(b * HW + p) * CIN + h * 32 + sub * 8);
    *(ushort4*)ob       = h0;
    *(ushort4*)(ob + 4) = h1;
}

// ---------------------------------------------------------------------------
extern "C" void kernel_launch(void* const* d_in, const int* in_sizes, int n_in,
                              void* d_out, int out_size, void* d_ws, size_t ws_size,
                              hipStream_t stream)
{
    const float* x     = (const float*)d_in[0];
    const float* wq    = (const float*)d_in[1];
    const float* wk    = (const float*)d_in[2];
    const float* wv    = (const float*)d_in[3];
    const float* pos   = (const float*)d_in[4];
    const float* wproj = (const float*)d_in[5];

    char* ws = (char*)d_ws;
    unsigned short* xt   = (unsigned short*)(ws);
    unsigned short* wb   = (unsigned short*)(ws + 2408448);
    float*          qkv  = (float*)        (ws + 2703360);
    unsigned short* oact = (unsigned short*)(ws + 17154048);
    float* out = (float*)d_out;

    prep_kernel<<<dim3(49, 3, 3), 256, 0, stream>>>(x, wq, wk, wv, wproj, xt, wb);
    // qkv: A=XT (m=p), B=WB rows 0..575 (n=o) -> QKV[b][p][576]
    gemm64<<<dim3(49, 9, 2), 256, 0, stream>>>(
        xt, (long)HW * CIN, wb, 0L, qkv, (long)HW * QKVLD, QKVLD);
    attn_kernel<<<dim3(7, 7, 12), 256, 0, stream>>>(qkv, pos, oact);
    // proj: A=wproj rows (m=o), B=o_act (n=p) -> out[b][o][p]
    gemm64<<<dim3(3, 49, 2), 256, 0, stream>>>(
        wb + 576 * CIN, 0L, oact, (long)HW * CIN, out, (long)CIN * HW, HW);
}